// Round 7
// baseline (469.197 us; speedup 1.0000x reference)
//
#include <hip/hip_runtime.h>
#include <hip/hip_bf16.h>
#include <stdint.h>

typedef short s16x8 __attribute__((ext_vector_type(8)));
typedef unsigned short u16x8 __attribute__((ext_vector_type(8)));
typedef float f32x4 __attribute__((ext_vector_type(4)));

__device__ __forceinline__ unsigned short f2bf(float f) {
    union { float f; unsigned u; } v; v.f = f;
    unsigned u = v.u;
    unsigned r = u + 0x7fffu + ((u >> 16) & 1u);
    return (unsigned short)(r >> 16);
}
__device__ __forceinline__ float bf2f(unsigned short h) {
    union { unsigned u; float f; } v; v.u = ((unsigned)h) << 16;
    return v.f;
}
__device__ __forceinline__ unsigned pkbf(float a, float b) {
    __hip_bfloat162 h = __float22bfloat162_rn(float2{a, b});
    union { __hip_bfloat162 h; unsigned u; } c; c.h = h; return c.u;
}
__device__ __forceinline__ float lo2f(unsigned d) {
    union { unsigned u; float f; } v; v.u = d << 16; return v.f;
}
__device__ __forceinline__ float hi2f(unsigned d) {
    union { unsigned u; float f; } v; v.u = d & 0xffff0000u; return v.f;
}

// ---------------------------------------------------------------------------
// K0: weight repack (fp32 OIHW -> bf16 [kpos][oc][ic]), d5w -> bf16
// ---------------------------------------------------------------------------
__global__ void k0_prep(const float* __restrict__ c2w, const float* __restrict__ c3w,
                        const float* __restrict__ c4w, const float* __restrict__ d5w,
                        unsigned short* __restrict__ w2, unsigned short* __restrict__ w3,
                        unsigned short* __restrict__ w4, unsigned short* __restrict__ w5) {
    int t = blockIdx.x * 256 + threadIdx.x;
    if (t < 18432) {            // w2 [9][64][32] <- c2w [64][32][3][3]
        int kpos = t / 2048, rem = t % 2048, oc = rem / 32, ic = rem % 32;
        w2[t] = f2bf(c2w[(oc * 32 + ic) * 9 + kpos]);
        return;
    }
    t -= 18432;
    if (t < 36864) {            // w3 [9][64][64] <- c3w [64][64][3][3]
        int kpos = t / 4096, rem = t % 4096, oc = rem / 64, ic = rem % 64;
        w3[t] = f2bf(c3w[(oc * 64 + ic) * 9 + kpos]);
        return;
    }
    t -= 36864;
    if (t < 32768) {            // w4 [4][128][64] <- c4w [128][64][2][2]
        int kpos = t / 8192, rem = t % 8192, oc = rem / 64, ic = rem % 64;
        w4[t] = f2bf(c4w[(oc * 64 + ic) * 4 + kpos]);
        return;
    }
    t -= 32768;
    if (t < 294912) w5[t] = f2bf(d5w[t]);   // [256][1152] bf16
}

// ---------------------------------------------------------------------------
// K1 (R7): same as R4 but __launch_bounds__(256,6) — LDS 24.8 KB permits
// 6 blocks/CU; the (256,4) cap was the measured 47% occupancy ceiling.
// ---------------------------------------------------------------------------
__global__ __launch_bounds__(256, 6)
void k1_conv1(const float* __restrict__ x, const float* __restrict__ c1w,
              const float* __restrict__ c1b, const float* __restrict__ a1,
              unsigned short* __restrict__ p1) {
    __shared__ unsigned xstrip[3 * 7 * 48];      // [ic][7 rows][48] h|l<<16  (4 KB)
    __shared__ unsigned short cbuf[230 * 40];    // [flat px][32 oc + 8 pad]  (18.4 KB)
    __shared__ unsigned short wlds[1024];        // [32 oc][32 k], k>=27 zero (2 KB)
    __shared__ float bls[32], als[32];

    const int n = blockIdx.x, tid = threadIdx.x;
    const int w = tid >> 6, lane = tid & 63, q = lane >> 4, l16 = lane & 15;

    for (int t = tid; t < 1024; t += 256) {
        int oc = t >> 5, k = t & 31;
        wlds[t] = (k < 27) ? f2bf(c1w[oc * 27 + k]) : (unsigned short)0;
    }
    if (tid < 32) { bls[tid] = c1b[tid]; als[tid] = a1[tid]; }
    __syncthreads();

    s16x8 Wf[2];
    #pragma unroll
    for (int nt = 0; nt < 2; ++nt)
        Wf[nt] = *(const s16x8*)(wlds + (nt * 16 + l16) * 32 + q * 8);

    float bq[2][4], aq[2][4];
    #pragma unroll
    for (int nt = 0; nt < 2; ++nt)
    #pragma unroll
    for (int r = 0; r < 4; ++r) {
        bq[nt][r] = bls[nt * 16 + q * 4 + r];
        aq[nt][r] = als[nt * 16 + q * 4 + r];
    }

    int off[8];
    #pragma unroll
    for (int j = 0; j < 8; ++j) {
        int k = q * 8 + j;
        int kk = k < 27 ? k : 26;
        int ic = kk / 9, r9 = kk - ic * 9, ky = r9 / 3, kx = r9 - ky * 3;
        off[j] = ic * 336 + ky * 48 + kx;
    }

    auto do_pool = [&](int sp, int nprows, int kymax) {
        int ntask = nprows * 92;
        int t = tid;
        if (t < ntask) {
            int ocg = t & 3; unsigned r2 = (unsigned)t >> 2;
            int px = (int)(r2 % 23u), py_l = (int)(r2 / 23u);
            int kxmax = (px == 22) ? 2 : 3;
            int base = (2 * py_l * 46 + 2 * px) * 40 + ocg * 8;
            float m0 = -3e38f, m1 = -3e38f, m2 = -3e38f, m3 = -3e38f;
            float m4 = -3e38f, m5 = -3e38f, m6 = -3e38f, m7 = -3e38f;
            #pragma unroll
            for (int ky = 0; ky < 3; ++ky) {
                if (ky < kymax) {
                    #pragma unroll
                    for (int kx = 0; kx < 3; ++kx) {
                        if (kx < kxmax) {
                            uint4 d = *(const uint4*)&cbuf[base + (ky * 46 + kx) * 40];
                            m0 = fmaxf(m0, lo2f(d.x)); m1 = fmaxf(m1, hi2f(d.x));
                            m2 = fmaxf(m2, lo2f(d.y)); m3 = fmaxf(m3, hi2f(d.y));
                            m4 = fmaxf(m4, lo2f(d.z)); m5 = fmaxf(m5, hi2f(d.z));
                            m6 = fmaxf(m6, lo2f(d.w)); m7 = fmaxf(m7, hi2f(d.w));
                        }
                    }
                }
            }
            uint4 ov;
            ov.x = pkbf(m0, m1); ov.y = pkbf(m2, m3);
            ov.z = pkbf(m4, m5); ov.w = pkbf(m6, m7);
            int py = 2 * sp + py_l;
            *(uint4*)&p1[n * 16928 + (py * 23 + px) * 32 + ocg * 8] = ov;
        }
    };

    for (int s = 0; s < 12; ++s) {
        const int nrows = (s == 11) ? 2 : 5;
        const int P = 46 * nrows;
        const int ntiles = (P + 15) >> 4;
        const int xr0 = 4 * s;

        for (int t = tid; t < 1008; t += 256) {
            int ic = t / 336, rem = t - ic * 336;
            int rr = rem / 48, col = rem - rr * 48;
            int row = xr0 + rr; if (row > 47) row = 47;
            float f = x[n * 6912 + ic * 2304 + row * 48 + col];
            unsigned short h = f2bf(f);
            unsigned short l = f2bf(f - bf2f(h));
            xstrip[t] = (unsigned)h | ((unsigned)l << 16);
        }
        if (s > 0) do_pool(s - 1, 2, 3);
        __syncthreads();

        for (int T = w; T < ntiles; T += 4) {
            int px = T * 16 + l16;
            int p = px < P ? px : P - 1;
            int ry = p / 46, cx = p - ry * 46;
            int basex = ry * 48 + cx;
            unsigned vv[8];
            #pragma unroll
            for (int j = 0; j < 8; ++j) vv[j] = xstrip[basex + off[j]];
            s16x8 Xh, Xl;
            #pragma unroll
            for (int j = 0; j < 8; ++j) {
                Xh[j] = (short)(vv[j] & 0xffffu);
                Xl[j] = (short)(vv[j] >> 16);
            }
            f32x4 acc[2] = {{0.f,0.f,0.f,0.f},{0.f,0.f,0.f,0.f}};
            #pragma unroll
            for (int nt = 0; nt < 2; ++nt) {
                acc[nt] = __builtin_amdgcn_mfma_f32_16x16x32_bf16(Wf[nt], Xh, acc[nt], 0, 0, 0);
                acc[nt] = __builtin_amdgcn_mfma_f32_16x16x32_bf16(Wf[nt], Xl, acc[nt], 0, 0, 0);
            }
            if (px < P) {
                #pragma unroll
                for (int nt = 0; nt < 2; ++nt) {
                    float v0 = acc[nt][0] + bq[nt][0];
                    float v1 = acc[nt][1] + bq[nt][1];
                    float v2 = acc[nt][2] + bq[nt][2];
                    float v3 = acc[nt][3] + bq[nt][3];
                    v0 = fmaxf(v0, 0.f) + aq[nt][0] * fminf(v0, 0.f);
                    v1 = fmaxf(v1, 0.f) + aq[nt][1] * fminf(v1, 0.f);
                    v2 = fmaxf(v2, 0.f) + aq[nt][2] * fminf(v2, 0.f);
                    v3 = fmaxf(v3, 0.f) + aq[nt][3] * fminf(v3, 0.f);
                    uint2 pk; pk.x = pkbf(v0, v1); pk.y = pkbf(v2, v3);
                    *(uint2*)&cbuf[px * 40 + nt * 16 + q * 4] = pk;
                }
            }
        }
        __syncthreads();
    }
    do_pool(11, 1, 2);
}

// ---------------------------------------------------------------------------
// K23 (R7): fused conv2+pool2+conv3+pool3+conv4. xs staging REMOVED — conv2
// A-fragments are b128 global reads from p1 (19 KB window, L1/L2-hot; kp
// offsets fold into load immediates). LDS 65.5 -> 46 KB -> 3 blocks/CU;
// barriers 8 -> 6.
// LDS map: c2s [231][72] @ 0 (33264 B) | p2s [100][64] @ 33264 (12800 B)
//          c3buf [64][64] @ 0, p3 [16][64] @ 8192 (alias dead c2s)
// ---------------------------------------------------------------------------
__global__ __launch_bounds__(256, 3)
void k23_fused(const unsigned short* __restrict__ p1, const unsigned short* __restrict__ w2,
               const float* __restrict__ c2b, const float* __restrict__ a2,
               const unsigned short* __restrict__ w3, const float* __restrict__ c3b,
               const float* __restrict__ a3, const unsigned short* __restrict__ w4,
               const float* __restrict__ c4b, const float* __restrict__ a4,
               unsigned short* __restrict__ flat) {
    __shared__ __align__(16) char smem[46064];
    unsigned short* c2s   = (unsigned short*)(smem);            // [231][72]
    unsigned short* p2s   = (unsigned short*)(smem + 33264);    // [100][64]
    unsigned short* c3buf = (unsigned short*)(smem);            // alias (8 KB)
    unsigned short* p3    = (unsigned short*)(smem + 8192);     // alias (2 KB)

    const int n = blockIdx.x, tid = threadIdx.x;
    const int w = tid >> 6, lane = tid & 63, q = lane >> 4, l16 = lane & 15;
    const unsigned short* p1n = p1 + n * 16928;

    // conv2 B fragments: [9 kpos][4 nt], oc = nt*16+l16, ic = q*8..q*8+7
    s16x8 Bf[36];
    #pragma unroll
    for (int kp = 0; kp < 9; ++kp)
    #pragma unroll
    for (int nt = 0; nt < 4; ++nt) {
        int oc = nt * 16 + l16;
        Bf[kp * 4 + nt] = *(const s16x8*)(w2 + (kp * 64 + oc) * 32 + q * 8);
    }
    float b2r[4], a2r[4];
    #pragma unroll
    for (int nt = 0; nt < 4; ++nt) { b2r[nt] = c2b[nt * 16 + l16]; a2r[nt] = a2[nt * 16 + l16]; }

    // conv2 half: conv rows row0..row0+10 (231 px), A direct from global
    auto conv2_half = [&](int row0) {
        for (int T = w; T < 15; T += 4) {
            int m = T * 16 + l16;
            int p = m < 231 ? m : 230;
            int oy = p / 21, ox = p - oy * 21;
            const unsigned short* ap = p1n + ((row0 + oy) * 23 + ox) * 32 + q * 8;
            f32x4 acc[4] = {{0.f,0.f,0.f,0.f},{0.f,0.f,0.f,0.f},
                            {0.f,0.f,0.f,0.f},{0.f,0.f,0.f,0.f}};
            #pragma unroll
            for (int kp = 0; kp < 9; ++kp) {
                int ky = kp / 3, kx = kp % 3;
                s16x8 A = *(const s16x8*)(ap + (ky * 23 + kx) * 32);
                #pragma unroll
                for (int nt = 0; nt < 4; ++nt)
                    acc[nt] = __builtin_amdgcn_mfma_f32_16x16x32_bf16(A, Bf[kp * 4 + nt], acc[nt], 0, 0, 0);
            }
            #pragma unroll
            for (int nt = 0; nt < 4; ++nt) {
                int oc = nt * 16 + l16;
                #pragma unroll
                for (int r = 0; r < 4; ++r) {
                    int row = T * 16 + q * 4 + r;
                    if (row < 231) {
                        float val = acc[nt][r] + b2r[nt];
                        val = fmaxf(val, 0.f) + a2r[nt] * fminf(val, 0.f);
                        c2s[row * 72 + oc] = f2bf(val);
                    }
                }
            }
        }
    };

    // pool2 half: 5 pool rows (py0..py0+4) from c2s local rows 0..10
    auto pool_half = [&](int py0) {
        for (int t = tid; t < 400; t += 256) {
            int ocg = t & 7; int r2 = t >> 3;
            int px = r2 % 10, pyl = r2 / 10;
            int base = (pyl * 2 * 21 + px * 2) * 72 + ocg * 8;
            float m0 = -3e38f, m1 = -3e38f, m2 = -3e38f, m3 = -3e38f;
            float m4 = -3e38f, m5 = -3e38f, m6 = -3e38f, m7 = -3e38f;
            #pragma unroll
            for (int ky = 0; ky < 3; ++ky)
            #pragma unroll
            for (int kx = 0; kx < 3; ++kx) {
                uint4 d = *(const uint4*)&c2s[base + (ky * 21 + kx) * 72];
                m0 = fmaxf(m0, lo2f(d.x)); m1 = fmaxf(m1, hi2f(d.x));
                m2 = fmaxf(m2, lo2f(d.y)); m3 = fmaxf(m3, hi2f(d.y));
                m4 = fmaxf(m4, lo2f(d.z)); m5 = fmaxf(m5, hi2f(d.z));
                m6 = fmaxf(m6, lo2f(d.w)); m7 = fmaxf(m7, hi2f(d.w));
            }
            uint4 ov;
            ov.x = pkbf(m0, m1); ov.y = pkbf(m2, m3);
            ov.z = pkbf(m4, m5); ov.w = pkbf(m6, m7);
            *(uint4*)&p2s[((py0 + pyl) * 10 + px) * 64 + ocg * 8] = ov;
        }
    };

    conv2_half(0);            // conv rows 0..10
    __syncthreads();
    pool_half(0);             // pool rows 0..4
    __syncthreads();
    conv2_half(10);           // conv rows 10..20
    __syncthreads();
    pool_half(5);             // pool rows 5..9
    __syncthreads();

    // conv3 (64 px, K=576: 18 chunks), reads p2s -> c3buf
    {
        int px = w * 16 + l16;
        int oy = px >> 3, ox = px & 7;
        s16x8 Af[18];
        #pragma unroll
        for (int c = 0; c < 18; ++c) {
            int kp = c >> 1, ky = kp / 3, kx = kp % 3;
            int ic0 = (c & 1) * 32 + q * 8;
            Af[c] = *(const s16x8*)(p2s + ((oy + ky) * 10 + ox + kx) * 64 + ic0);
        }
        #pragma unroll
        for (int nt = 0; nt < 4; ++nt) {
            int oc = nt * 16 + l16;
            f32x4 acc = {0.f, 0.f, 0.f, 0.f};
            #pragma unroll
            for (int c = 0; c < 18; ++c) {
                int kp = c >> 1;
                int ic0 = (c & 1) * 32 + q * 8;
                s16x8 B = *(const s16x8*)(w3 + (kp * 64 + oc) * 64 + ic0);
                acc = __builtin_amdgcn_mfma_f32_16x16x32_bf16(Af[c], B, acc, 0, 0, 0);
            }
            float bias = c3b[oc], al = a3[oc];
            #pragma unroll
            for (int r = 0; r < 4; ++r) {
                int row = w * 16 + q * 4 + r;
                float val = acc[r] + bias;
                val = fmaxf(val, 0.f) + al * fminf(val, 0.f);
                c3buf[row * 64 + oc] = f2bf(val);
            }
        }
    }
    __syncthreads();

    // pool3 2x2 s2 (8->4) -> p3
    for (int t = tid; t < 1024; t += 256) {
        int oc = t & 63, r = t >> 6, py = r >> 2, pxo = r & 3;
        float m = -3e38f;
        #pragma unroll
        for (int ky = 0; ky < 2; ++ky)
        #pragma unroll
        for (int kx = 0; kx < 2; ++kx)
            m = fmaxf(m, bf2f(c3buf[((py * 2 + ky) * 8 + pxo * 2 + kx) * 64 + oc]));
        p3[t] = f2bf(m);
    }
    __syncthreads();

    // conv4 (M=9 pad16, N=128, K=256: 8 chunks) -> permuted flat
    {
        int m = l16, px = m < 9 ? m : 8;
        int oy = px / 3, ox = px % 3;
        s16x8 Af[8];
        #pragma unroll
        for (int c = 0; c < 8; ++c) {
            int kp = c >> 1, ky = kp >> 1, kx = kp & 1;
            int ic0 = (c & 1) * 32 + q * 8;
            Af[c] = *(const s16x8*)(p3 + ((oy + ky) * 4 + ox + kx) * 64 + ic0);
        }
        #pragma unroll
        for (int h = 0; h < 2; ++h) {
            int nt = w * 2 + h, oc = nt * 16 + l16;
            f32x4 acc = {0.f, 0.f, 0.f, 0.f};
            #pragma unroll
            for (int c = 0; c < 8; ++c) {
                int kp = c >> 1;
                int ic0 = (c & 1) * 32 + q * 8;
                s16x8 B = *(const s16x8*)(w4 + (kp * 128 + oc) * 64 + ic0);
                acc = __builtin_amdgcn_mfma_f32_16x16x32_bf16(Af[c], B, acc, 0, 0, 0);
            }
            float bias = c4b[oc], al = a4[oc];
            #pragma unroll
            for (int r = 0; r < 4; ++r) {
                int row = q * 4 + r;
                if (row < 9) {
                    int hy = row / 3, wx = row % 3;
                    float val = acc[r] + bias;
                    val = fmaxf(val, 0.f) + al * fminf(val, 0.f);
                    flat[(unsigned)n * 1152u + (wx * 3 + hy) * 128 + oc] = f2bf(val);
                }
            }
        }
    }
}

// ---------------------------------------------------------------------------
// K5a (R7): d5 GEMM half — 256 blocks, block = 16 images x 128 oc.
// K=1152 split over 4 waves (9 chunks each); LDS reduce; bias+PReLU;
// h -> ws as bf16 [2048][256].
// ---------------------------------------------------------------------------
__global__ __launch_bounds__(256, 2)
void k5a_gemm(const unsigned short* __restrict__ flat, const unsigned short* __restrict__ w5,
              const float* __restrict__ d5b, const float* __restrict__ a5,
              unsigned short* __restrict__ h) {
    __shared__ float hbuf[4 * 16 * 128];   // 32 KB
    const int blk = blockIdx.x, tid = threadIdx.x;
    const int w = tid >> 6, lane = tid & 63, q = lane >> 4, l16 = lane & 15;
    const int img0 = (blk >> 1) * 16, ocb = (blk & 1) * 128;
    const int img = img0 + l16;

    f32x4 acc[8];
    #pragma unroll
    for (int nt = 0; nt < 8; ++nt) acc[nt] = f32x4{0.f, 0.f, 0.f, 0.f};

    for (int cc = 0; cc < 9; ++cc) {
        int c = w * 9 + cc;
        int k0 = c * 32 + q * 8;
        s16x8 A = *(const s16x8*)(flat + (unsigned)img * 1152u + k0);
        #pragma unroll
        for (int nt = 0; nt < 8; ++nt) {
            int oc = ocb + nt * 16 + l16;
            s16x8 B = *(const s16x8*)(w5 + (unsigned)oc * 1152u + k0);
            acc[nt] = __builtin_amdgcn_mfma_f32_16x16x32_bf16(A, B, acc[nt], 0, 0, 0);
        }
    }
    #pragma unroll
    for (int nt = 0; nt < 8; ++nt)
    #pragma unroll
    for (int r = 0; r < 4; ++r) {
        int row = q * 4 + r;               // image within tile
        hbuf[(w * 16 + row) * 128 + nt * 16 + l16] = acc[nt][r];
    }
    __syncthreads();
    for (int t = tid; t < 1024; t += 256) {
        int im = t >> 6, oc2 = (t & 63) * 2;
        float s0 = hbuf[im * 128 + oc2]       + hbuf[(16 + im) * 128 + oc2]
                 + hbuf[(32 + im) * 128 + oc2] + hbuf[(48 + im) * 128 + oc2];
        float s1 = hbuf[im * 128 + oc2 + 1]       + hbuf[(16 + im) * 128 + oc2 + 1]
                 + hbuf[(32 + im) * 128 + oc2 + 1] + hbuf[(48 + im) * 128 + oc2 + 1];
        int oc = ocb + oc2;
        s0 += d5b[oc];     s0 = fmaxf(s0, 0.f) + a5[oc] * fminf(s0, 0.f);
        s1 += d5b[oc + 1]; s1 = fmaxf(s1, 0.f) + a5[oc + 1] * fminf(s1, 0.f);
        *(unsigned*)&h[(unsigned)(img0 + im) * 256u + oc] = pkbf(s0, s1);
    }
}

// ---------------------------------------------------------------------------
// K5b (R7): heads from h — 128 blocks x 16 images. h rows and all 16 head
// weight rows staged in LDS (stride 260: 16B-aligned float4, 2-way-max bank
// aliasing = free). Dot = 64 iters of 2x ds_read_b128 + 4 fma.
// Output: b[2048x4] @0 | c[2048x10] @8192 | a[2048x2] @28672
// ---------------------------------------------------------------------------
__global__ __launch_bounds__(256, 2)
void k5b_head(const unsigned short* __restrict__ h,
              const float* __restrict__ d61w, const float* __restrict__ d61b,
              const float* __restrict__ d62w, const float* __restrict__ d62b,
              const float* __restrict__ d63w, const float* __restrict__ d63b,
              float* __restrict__ out) {
    __shared__ float hL[16 * 260];         // 16.6 KB
    __shared__ float wl[16 * 260];         // 16.6 KB
    __shared__ float lg[256];
    const int blk = blockIdx.x, tid = threadIdx.x;
    const int img0 = blk * 16;

    // stage h (16 img x 256 bf16) -> fp32
    for (int t = tid; t < 512; t += 256) {
        int im = t >> 5, g = t & 31;
        uint4 d = *(const uint4*)&h[(unsigned)(img0 + im) * 256u + g * 8];
        float* dst = &hL[im * 260 + g * 8];
        dst[0] = lo2f(d.x); dst[1] = hi2f(d.x);
        dst[2] = lo2f(d.y); dst[3] = hi2f(d.y);
        dst[4] = lo2f(d.z); dst[5] = hi2f(d.z);
        dst[6] = lo2f(d.w); dst[7] = hi2f(d.w);
    }
    // stage 16 head weight rows (fp32)
    {
        int o = tid >> 4, seg = tid & 15;
        const float* wrow = (o < 2) ? d61w + o * 256
                          : (o < 6) ? d62w + (o - 2) * 256
                          :           d63w + (o - 6) * 256;
        #pragma unroll
        for (int j = 0; j < 4; ++j)
            *(float4*)&wl[o * 260 + seg * 16 + j * 4] = ((const float4*)wrow)[seg * 4 + j];
    }
    __syncthreads();

    const int im = tid >> 4, o = tid & 15;
    {
        float bias = (o < 2) ? d61b[o] : (o < 6) ? d62b[o - 2] : d63b[o - 6];
        float s = bias;
        const float4* ha = (const float4*)&hL[im * 260];
        const float4* wa = (const float4*)&wl[o * 260];
        #pragma unroll 8
        for (int k = 0; k < 64; ++k) {
            float4 a = ha[k], b = wa[k];
            s += a.x * b.x + a.y * b.y + a.z * b.z + a.w * b.w;
        }
        lg[im * 16 + o] = s;
    }
    __syncthreads();
    {
        int gimg = img0 + im;
        float v = lg[im * 16 + o];
        if (o >= 2 && o < 6) {
            out[gimg * 4 + (o - 2)] = v;                       // b [N,4]
        } else if (o >= 6) {
            out[8192 + gimg * 10 + (o - 6)] = v;               // c [N,10]
        } else {
            float l0 = lg[im * 16 + 0], l1 = lg[im * 16 + 1];
            float mx = fmaxf(l0, l1);
            float e0 = __expf(l0 - mx), e1 = __expf(l1 - mx);
            out[28672 + gimg * 2 + o] = (o == 0 ? e0 : e1) / (e0 + e1);   // a [N,2]
        }
    }
}

// ---------------------------------------------------------------------------
extern "C" void kernel_launch(void* const* d_in, const int* in_sizes, int n_in,
                              void* d_out, int out_size, void* d_ws, size_t ws_size,
                              hipStream_t stream) {
    (void)in_sizes; (void)n_in; (void)out_size; (void)ws_size;
    const float* x    = (const float*)d_in[0];
    const float* c1w  = (const float*)d_in[1];
    const float* c1b  = (const float*)d_in[2];
    const float* a1   = (const float*)d_in[3];
    const float* c2w  = (const float*)d_in[4];
    const float* c2b  = (const float*)d_in[5];
    const float* a2   = (const float*)d_in[6];
    const float* c3w  = (const float*)d_in[7];
    const float* c3b  = (const float*)d_in[8];
    const float* a3   = (const float*)d_in[9];
    const float* c4w  = (const float*)d_in[10];
    const float* c4b  = (const float*)d_in[11];
    const float* a4   = (const float*)d_in[12];
    const float* d5w  = (const float*)d_in[13];
    const float* d5b  = (const float*)d_in[14];
    const float* a5   = (const float*)d_in[15];
    const float* d61w = (const float*)d_in[16];
    const float* d61b = (const float*)d_in[17];
    const float* d62w = (const float*)d_in[18];
    const float* d62b = (const float*)d_in[19];
    const float* d63w = (const float*)d_in[20];
    const float* d63b = (const float*)d_in[21];

    char* ws = (char*)d_ws;
    // region plan:
    //   p1    @ 0          : 69,337,088 B  (live through k23_fused)
    //   flat  @ 69,337,088 : 4,718,592 B
    //   h     @ 74,055,680 : 1,048,576 B
    //   weights @ 186,777,600 : ~766 KB
    unsigned short* p1    = (unsigned short*)(ws + 0);
    unsigned short* flat  = (unsigned short*)(ws + 69337088);
    unsigned short* h     = (unsigned short*)(ws + 74055680);
    unsigned short* w2    = (unsigned short*)(ws + 186777600);
    unsigned short* w3    = (unsigned short*)(ws + 186814464);
    unsigned short* w4    = (unsigned short*)(ws + 186888192);
    unsigned short* w5    = (unsigned short*)(ws + 186953728);

    k0_prep  <<<1496, 256, 0, stream>>>(c2w, c3w, c4w, d5w, w2, w3, w4, w5);
    k1_conv1 <<<2048, 256, 0, stream>>>(x, c1w, c1b, a1, p1);
    k23_fused<<<2048, 256, 0, stream>>>(p1, w2, c2b, a2, w3, c3b, a3, w4, c4b, a4, flat);
    k5a_gemm <<<256, 256, 0, stream>>>(flat, w5, d5b, a5, h);
    k5b_head <<<128, 256, 0, stream>>>(h, d61w, d61b, d62w, d62b, d63w, d63b,
                                       (float*)d_out);
}